// Round 6
// baseline (532.736 us; speedup 1.0000x reference)
//
#include <hip/hip_runtime.h>
#include <hip/hip_bf16.h>
#include <hip/hip_cooperative_groups.h>

namespace cg = cooperative_groups;

#define N 8192
#define OD 64
#define E_EDGES 262144

#define BM 64
#define KSPLIT 8
#define KS_PER_SPLIT (N / KSPLIT)   // 1024
#define GRID_BLOCKS 1024            // 4 blocks/CU x 256 CU, co-resident (launch_bounds 256,4)
#define NORM_BLOCKS2 512            // phase-2 split: blocks [0,512) norm, [512,1024) scatter

typedef __attribute__((ext_vector_type(8))) short bf16x8;
typedef __attribute__((ext_vector_type(4))) float f32x4;

__device__ __forceinline__ unsigned short f2bf(float f) {
    union { float f; unsigned u; } v; v.f = f;
    unsigned r = (v.u + 0x7fffu + ((v.u >> 16) & 1u)) >> 16;  // RNE
    return (unsigned short)r;
}

__global__ __launch_bounds__(256, 4) void mega_kernel(
        const float* __restrict__ x, const float* __restrict__ attn,
        const float* __restrict__ w, const float* __restrict__ values,
        const int* __restrict__ row, const int* __restrict__ col,
        unsigned short* __restrict__ wt, float* __restrict__ y,
        float* __restrict__ part, float* __restrict__ out,
        float* __restrict__ out_norm) {
    cg::grid_group grid = cg::this_grid();
    const int bid = blockIdx.x;
    const int t = threadIdx.x;

    // ================= P0: zero y & out; convert W [N][OD] f32 -> wt [OD][N] bf16 ====
    {
        int zi = bid * 256 + t;   // 262144 float4 = y (131072) ++ out (131072)
        float4 z{0.f, 0.f, 0.f, 0.f};
        if (zi < 131072) ((float4*)y)[zi] = z;
        else             ((float4*)out)[zi - 131072] = z;

        if (t < 64) {             // block owns k-range [bid*8, bid*8+8)
            const int kb = bid * 8;
            bf16x8 v;
            #pragma unroll
            for (int j = 0; j < 8; ++j)
                v[j] = (short)f2bf(w[(size_t)(kb + j) * OD + t]);   // lanes coalesced over t
            *(bf16x8*)(wt + (size_t)t * N + kb) = v;
        }
    }
    grid.sync();

    // ================= P1: y += x[:,split] @ W[split,:] — register-only MFMA =========
    {
        const int wv = t >> 6;
        const int lane = t & 63;
        const int lrow = lane & 15;   // A-row / B-col within 16x16 fragment
        const int g = lane >> 4;      // k-group (8 elems)
        const int rt = bid >> 3;      // row-tile 0..127
        const int split = bid & 7;
        const int rowi = rt * BM + wv * 16 + lrow;
        const int k0 = split * KS_PER_SPLIT;

        f32x4 acc[4] = {f32x4{0,0,0,0}, f32x4{0,0,0,0}, f32x4{0,0,0,0}, f32x4{0,0,0,0}};
        const float* xp = x + (size_t)rowi * N + k0 + g * 8;
        const unsigned short* wp = wt + k0 + g * 8;

        #pragma unroll 4
        for (int ks = 0; ks < KS_PER_SPLIT / 32; ++ks) {   // 32 iters
            float4 v0 = *(const float4*)(xp + ks * 32);
            float4 v1 = *(const float4*)(xp + ks * 32 + 4);
            bf16x8 a;
            a[0] = f2bf(v0.x); a[1] = f2bf(v0.y); a[2] = f2bf(v0.z); a[3] = f2bf(v0.w);
            a[4] = f2bf(v1.x); a[5] = f2bf(v1.y); a[6] = f2bf(v1.z); a[7] = f2bf(v1.w);
            #pragma unroll
            for (int cf = 0; cf < 4; ++cf) {
                bf16x8 b = *(const bf16x8*)(wp + (size_t)(cf * 16 + lrow) * N + ks * 32);
                acc[cf] = __builtin_amdgcn_mfma_f32_16x16x32_bf16(a, b, acc[cf], 0, 0, 0);
            }
        }
        // C/D layout: col = lane&15, row = (lane>>4)*4 + i (verified); split-K via atomics
        float* yp = y + ((size_t)rt * BM + wv * 16 + g * 4) * OD;
        #pragma unroll
        for (int cf = 0; cf < 4; ++cf) {
            #pragma unroll
            for (int i = 0; i < 4; ++i)
                atomicAdd(&yp[i * OD + cf * 16 + lrow], acc[cf][i]);
        }
    }
    grid.sync();

    // ================= P2: norm stream (blocks 0-511)  ||  edge scatter (512-1023) ===
    if (bid < NORM_BLOCKS2) {
        const float4* a4 = (const float4*)attn;
        const int total = (N * (long)N) / 4;           // 16,777,216
        float s = 0.f;
        for (long i = (long)bid * 256 + t; i < total; i += (long)NORM_BLOCKS2 * 256) {
            float4 v = a4[i];
            s += v.x * v.x + v.y * v.y + v.z * v.z + v.w * v.w;
        }
        for (int off = 32; off > 0; off >>= 1) s += __shfl_down(s, off, 64);
        __shared__ float wpart[4];
        int wid = t >> 6;
        if ((t & 63) == 0) wpart[wid] = s;
        __syncthreads();
        if (t == 0) part[bid] = wpart[0] + wpart[1] + wpart[2] + wpart[3];
    } else {
        const int lane = t & 63;
        int e = (bid - NORM_BLOCKS2) * 4 + (t >> 6);   // wave index 0..2047
        #pragma unroll 4
        for (int it = 0; it < E_EDGES / (NORM_BLOCKS2 * 4); ++it, e += NORM_BLOCKS2 * 4) {
            const int r = row[e];
            const int c = col[e];
            const float ev = values[e] * attn[(size_t)r * N + c];
            atomicAdd(&out[r * OD + lane], ev * y[c * OD + lane]);
        }
    }
    grid.sync();

    // ================= P3: finalize norm ============================================
    if (bid == 0) {
        float s = part[t] + part[t + 256];
        for (int off = 32; off > 0; off >>= 1) s += __shfl_down(s, off, 64);
        __shared__ float wp2[4];
        int wid = t >> 6;
        if ((t & 63) == 0) wp2[wid] = s;
        __syncthreads();
        if (t == 0) *out_norm = sqrtf(wp2[0] + wp2[1] + wp2[2] + wp2[3]);
    }
}

extern "C" void kernel_launch(void* const* d_in, const int* in_sizes, int n_in,
                              void* d_out, int out_size, void* d_ws, size_t ws_size,
                              hipStream_t stream) {
    const float* x      = (const float*)d_in[0];
    const float* attn   = (const float*)d_in[1];
    const float* weight = (const float*)d_in[2];
    const float* values = (const float*)d_in[3];
    const int*   row    = (const int*)d_in[4];
    const int*   col    = (const int*)d_in[5];
    float* out = (float*)d_out;

    char* wsb = (char*)d_ws;
    float*          part = (float*)wsb;                          // 2 KB (512 f32)
    unsigned short* wt   = (unsigned short*)(wsb + (1u << 20));  // 1 MB
    float*          y    = (float*)(wsb + (2u << 20));           // 2 MB
    float*          out_norm = out + (size_t)N * OD;

    void* args[] = {(void*)&x, (void*)&attn, (void*)&weight, (void*)&values,
                    (void*)&row, (void*)&col, (void*)&wt, (void*)&y,
                    (void*)&part, (void*)&out, (void*)&out_norm};
    hipLaunchCooperativeKernel((const void*)mega_kernel, dim3(GRID_BLOCKS), dim3(256),
                               args, 0, stream);
}